// Round 5
// baseline (143.360 us; speedup 1.0000x reference)
//
#include <hip/hip_runtime.h>
#include <stdint.h>

#define LL 256
#define DD 256
#define CH 32

typedef __attribute__((ext_vector_type(2))) _Float16 f16x2;
typedef __attribute__((ext_vector_type(8))) _Float16 halfx8;
typedef __attribute__((ext_vector_type(4))) float f32x4;

static __device__ __forceinline__ uint32_t pk16(float a, float b) {
  f16x2 p; p.x = (_Float16)a; p.y = (_Float16)b;   // RTN casts
  return __builtin_bit_cast(uint32_t, p);
}
static __device__ __forceinline__ f16x2 bc2(uint32_t u) { return __builtin_bit_cast(f16x2, u); }
static __device__ __forceinline__ halfx8 bc8(uint4 u) { return __builtin_bit_cast(halfx8, u); }

// ---------------------------------------------------------------------------
// Kernel P: one-time weight packing.
//  blocks [0,64):  W1 -> w1p f16 in MFMA-A-frag layout (d-permutation):
//    k-step s, lane-group g=(l>>4), frag t:
//      d  = 32*(s>>1) + 8*g + 4*(s&1) + 2*((t>>2)&1) + (t&1)
//      ko = (t&2) ? 256+d (absdiff row) : d (mul row)
//    flat[((s*2+hM)*64 + l)*8 + t] = W1[ko][16*hM + (l&15)]
//  block 64:       W2 -> w2p packed f16 pairs [(di*4+q)*7+dj]*4 + t,
//                  pair t = channels q*8+2t, q*8+2t+1
// ---------------------------------------------------------------------------
__global__ void bepler_pack(const float* __restrict__ W1, const float* __restrict__ W2,
                            _Float16* __restrict__ w1p, uint32_t* __restrict__ w2p) {
  const int gid = blockIdx.x * 256 + threadIdx.x;
  if (blockIdx.x < 64) {
    const int idx = gid;                   // 0..16383
    const int t  = idx & 7;
    const int l  = (idx >> 3) & 63;
    const int hM = (idx >> 9) & 1;
    const int s  = idx >> 10;
    const int g  = (l >> 4) & 3;
    const int d  = 32 * (s >> 1) + 8 * g + 4 * (s & 1) + 2 * ((t >> 2) & 1) + (t & 1);
    const int ko = (t & 2) ? (DD + d) : d;
    w1p[idx] = (_Float16)W1[ko * CH + 16 * hM + (l & 15)];
  } else {
    for (int k = threadIdx.x; k < 784; k += 256) {
      const int t  = k & 3;
      const int dj = (k >> 2) % 7;
      const int qd = (k >> 2) / 7;         // di*4+q
      const int q  = qd & 3;
      const int di = qd >> 2;
      const int c  = q * 8 + 2 * t;
      w2p[k] = pk16(W2[(di * 7 + dj) * 32 + c], W2[(di * 7 + dj) * 32 + c + 1]);
    }
  }
}

// ---------------------------------------------------------------------------
// Kernel A: h[b,i,j,c] = mask * relu( z . W1[:,c] + b1[c] ), f16 out.
// Tile 16i x 64j per block (grid 4x16x8 = 512 = 2 blocks/CU). Wave = 4 i-rows.
// Per m-step: 1 xi b128 (16-lane broadcast) + 4 xj b128 (conflict-free: row
// stride 35 granules, 3*m16 mod 8 covers all banks) feed 16 MFMA.
// afrags (full W1) register-resident from prepacked global (128 VGPR).
// x converted f32->f16 during staging (no separate pack pass).
// ---------------------------------------------------------------------------
#define XPAD 280   // f16/row = 560 B = 35 granules (odd) -> bank-uniform b128
__global__ __launch_bounds__(256, 2) void bepler_h_kernel(
    const float* __restrict__ x, const int* __restrict__ plen,
    const uint4* __restrict__ w1p4, const float* __restrict__ b1,
    _Float16* __restrict__ hws)
{
  __shared__ _Float16 xi[16 * XPAD];   // 8.75 KB
  __shared__ _Float16 xj[64 * XPAD];   // 35 KB

  const int tid  = threadIdx.x;
  const int lane = tid & 63;
  const int wave = tid >> 6;
  const int b  = blockIdx.z;
  const int i0 = blockIdx.y * 16;
  const int j0 = blockIdx.x * 64;
  const int g   = lane >> 4;
  const int m16 = lane & 15;

  // Full W1 A-fragments from prepacked global (coalesced, L2-hot): 128 VGPR
  uint4 af[16][2];
#pragma unroll
  for (int s = 0; s < 16; ++s) {
#pragma unroll
    for (int hM = 0; hM < 2; ++hM)
      af[s][hM] = w1p4[(s * 2 + hM) * 64 + lane];
  }

  // Stage x tiles: f32 global (coalesced float4) -> f16 LDS
  const float* xb = x + (size_t)b * LL * DD;
  for (int idx = tid; idx < 80 * 64; idx += 256) {
    const int f = idx & 63, row = idx >> 6;
    const int grow = (row < 16) ? (i0 + row) : (j0 + row - 16);
    const float4 v = *(const float4*)(xb + grow * DD + 4 * f);
    uint2 st; st.x = pk16(v.x, v.y); st.y = pk16(v.z, v.w);
    _Float16* dst = (row < 16) ? (xi + row * XPAD) : (xj + (row - 16) * XPAD);
    *(uint2*)(dst + 4 * f) = st;
  }

  const int len = plen[b];
  float b1v[2][4];
#pragma unroll
  for (int r = 0; r < 4; ++r) {
    b1v[0][r] = b1[g * 4 + r];        // c = (lane>>4)*4 + r        (hM=0)
    b1v[1][r] = b1[16 + g * 4 + r];   // c = 16 + (lane>>4)*4 + r   (hM=1)
  }
  __syncthreads();

  for (int iu = 0; iu < 4; ++iu) {
    const int r = wave * 4 + iu;       // i-row in tile
    f32x4 acc[4][2];                   // [jg][hM]
#pragma unroll
    for (int jg = 0; jg < 4; ++jg)
#pragma unroll
      for (int hM = 0; hM < 2; ++hM)
        acc[jg][hM] = (f32x4){0.f, 0.f, 0.f, 0.f};

#pragma unroll
    for (int m = 0; m < 8; ++m) {
      const int doff = 32 * m + 8 * g;
      const uint4 ua = *(const uint4*)(xi + r * XPAD + doff);   // broadcast
      const f16x2 a0 = bc2(ua.x), a1 = bc2(ua.y), a2 = bc2(ua.z), a3 = bc2(ua.w);
#pragma unroll
      for (int jg = 0; jg < 4; ++jg) {
        const uint4 uc = *(const uint4*)(xj + (jg * 16 + m16) * XPAD + doff);
        const f16x2 c0 = bc2(uc.x), c1 = bc2(uc.y), c2 = bc2(uc.z), c3 = bc2(uc.w);
        const f16x2 p0 = a0 * c0, p1 = a1 * c1, p2 = a2 * c2, p3 = a3 * c3;
        const uint32_t s0 = __builtin_bit_cast(uint32_t, a0 - c0) & 0x7FFF7FFFu;
        const uint32_t s1 = __builtin_bit_cast(uint32_t, a1 - c1) & 0x7FFF7FFFu;
        const uint32_t s2 = __builtin_bit_cast(uint32_t, a2 - c2) & 0x7FFF7FFFu;
        const uint32_t s3 = __builtin_bit_cast(uint32_t, a3 - c3) & 0x7FFF7FFFu;
        uint4 be, bo;
        be.x = __builtin_bit_cast(uint32_t, p0); be.y = s0;
        be.z = __builtin_bit_cast(uint32_t, p1); be.w = s1;
        bo.x = __builtin_bit_cast(uint32_t, p2); bo.y = s2;
        bo.z = __builtin_bit_cast(uint32_t, p3); bo.w = s3;
        const halfx8 bE = bc8(be), bO = bc8(bo);
        acc[jg][0] = __builtin_amdgcn_mfma_f32_16x16x32_f16(bc8(af[2 * m][0]),     bE, acc[jg][0], 0, 0, 0);
        acc[jg][1] = __builtin_amdgcn_mfma_f32_16x16x32_f16(bc8(af[2 * m][1]),     bE, acc[jg][1], 0, 0, 0);
        acc[jg][0] = __builtin_amdgcn_mfma_f32_16x16x32_f16(bc8(af[2 * m + 1][0]), bO, acc[jg][0], 0, 0, 0);
        acc[jg][1] = __builtin_amdgcn_mfma_f32_16x16x32_f16(bc8(af[2 * m + 1][1]), bO, acc[jg][1], 0, 0, 0);
      }
    }

    // D layout: c = 16*hM + (lane>>4)*4 + reg ; j = j0 + jg*16 + (lane&15)
    const int i = i0 + r;
#pragma unroll
    for (int jg = 0; jg < 4; ++jg) {
      const int j = j0 + jg * 16 + m16;
      const float msk = (i < len && j < len) ? 1.f : 0.f;
      _Float16* hp = hws + ((size_t)(b * LL + i) * LL + j) * CH + g * 4;
#pragma unroll
      for (int hM = 0; hM < 2; ++hM) {
        const f32x4 a = acc[jg][hM];
        uint2 st;
        st.x = pk16(fmaxf(a[0] + b1v[hM][0], 0.f) * msk,
                    fmaxf(a[1] + b1v[hM][1], 0.f) * msk);
        st.y = pk16(fmaxf(a[2] + b1v[hM][2], 0.f) * msk,
                    fmaxf(a[3] + b1v[hM][3], 0.f) * msk);
        *(uint2*)(hp + hM * 16) = st;
      }
    }
  }
}

// ---------------------------------------------------------------------------
// Kernel B: out[b,i,j] = mask * ( sum_{di,dj,c} h[..]*W2[di,dj,c] + b2 )
// 32x32 tile (grid 512 = 2 blocks/CU), halo 38x38, 2 ch-phases (16ch, 23.7KB
// each live, 47.4KB total). Thread = 1i x 4j outputs: 70 b128/4 outputs.
// Lane map ti=lane&31 -> granule residue 7*ti mod 8 covers all banks (free).
// Weights wave-uniform (r is loop-uniform) -> s_load; pk_fma f16 accumulators.
// ---------------------------------------------------------------------------
__global__ __launch_bounds__(256, 2) void bepler_conv_kernel(
    const _Float16* __restrict__ hws, const uint32_t* __restrict__ w2p,
    const float* __restrict__ b2, const int* __restrict__ plen,
    float* __restrict__ out)
{
  __shared__ _Float16 htile[2 * 38 * 39 * 8];   // 47,424 B

  const int tid = threadIdx.x;
  const int b   = blockIdx.z;
  const int i0  = blockIdx.y * 32;
  const int j0  = blockIdx.x * 32;
  const int ti  = tid & 31;        // output row in tile
  const int tj  = tid >> 5;        // output cols 4*tj .. 4*tj+3

  f16x2 acc[4][4];                 // [jj][ch-pair]
#pragma unroll
  for (int jj = 0; jj < 4; ++jj)
#pragma unroll
    for (int t = 0; t < 4; ++t) acc[jj][t] = (f16x2){(_Float16)0, (_Float16)0};

  for (int ph = 0; ph < 2; ++ph) {         // channel phases (16 ch each)
    if (ph) __syncthreads();               // drain phase-0 reads
    for (int idx = tid; idx < 2 * 38 * 38; idx += 256) {
      const int qq  = idx & 1;
      const int pos = idx >> 1;
      const int row = pos / 38, col = pos - row * 38;
      const int gi = i0 - 3 + row, gj = j0 - 3 + col;
      uint4 v = make_uint4(0u, 0u, 0u, 0u);
      if (gi >= 0 && gi < LL && gj >= 0 && gj < LL)
        v = *(const uint4*)(hws + (((size_t)(b * LL + gi) * LL + gj) * CH + ph * 16 + qq * 8));
      *(uint4*)(htile + ((qq * 38 + row) * 39 + col) * 8) = v;
    }
    __syncthreads();

    for (int r = 0; r < 7; ++r) {          // di = r (wave-uniform)
#pragma unroll
      for (int qq = 0; qq < 2; ++qq) {
        const _Float16* hrow = htile + ((qq * 38 + ti + r) * 39 + 4 * tj) * 8;
        const uint32_t* wr = w2p + ((r * 4 + ph * 2 + qq) * 7) * 4;  // uniform
#pragma unroll
        for (int c = 0; c < 10; ++c) {
          const uint4 u = *(const uint4*)(hrow + c * 8);
          const f16x2 h0 = bc2(u.x), h1 = bc2(u.y), h2 = bc2(u.z), h3 = bc2(u.w);
#pragma unroll
          for (int jj = 0; jj < 4; ++jj) {
            const int dj = c - jj;                   // compile-time
            if (dj >= 0 && dj < 7) {
              const uint32_t* w = wr + dj * 4;
              acc[jj][0] = __builtin_elementwise_fma(h0, bc2(w[0]), acc[jj][0]);
              acc[jj][1] = __builtin_elementwise_fma(h1, bc2(w[1]), acc[jj][1]);
              acc[jj][2] = __builtin_elementwise_fma(h2, bc2(w[2]), acc[jj][2]);
              acc[jj][3] = __builtin_elementwise_fma(h3, bc2(w[3]), acc[jj][3]);
            }
          }
        }
      }
    }
  }

  const int i = i0 + ti;
  const int jb = j0 + 4 * tj;
  const int len = plen[b];
  const float bias = b2[0];
  float4 o;
  float s[4];
#pragma unroll
  for (int jj = 0; jj < 4; ++jj) {
    float v = 0.f;
#pragma unroll
    for (int t = 0; t < 4; ++t) v += (float)acc[jj][t].x + (float)acc[jj][t].y;
    s[jj] = v;
  }
  o.x = (i < len && (jb + 0) < len) ? s[0] + bias : 0.f;
  o.y = (i < len && (jb + 1) < len) ? s[1] + bias : 0.f;
  o.z = (i < len && (jb + 2) < len) ? s[2] + bias : 0.f;
  o.w = (i < len && (jb + 3) < len) ? s[3] + bias : 0.f;
  *(float4*)(out + (size_t)(b * LL + i) * LL + jb) = o;
}

extern "C" void kernel_launch(void* const* d_in, const int* in_sizes, int n_in,
                              void* d_out, int out_size, void* d_ws, size_t ws_size,
                              hipStream_t stream) {
  const float* x   = (const float*)d_in[0];
  const int*   pl  = (const int*)d_in[1];
  const float* W1  = (const float*)d_in[2];
  const float* b1  = (const float*)d_in[3];
  const float* W2  = (const float*)d_in[4];
  const float* b2  = (const float*)d_in[5];
  float* out = (float*)d_out;

  _Float16* hws = (_Float16*)d_ws;                      // 33,554,432 B
  _Float16* w1p = (_Float16*)((char*)d_ws + 33554432);  // 32,768 B
  uint32_t* w2p = (uint32_t*)((char*)d_ws + 33587200);  // 3,136 B

  bepler_pack<<<dim3(65), dim3(256), 0, stream>>>(W1, W2, w1p, w2p);
  dim3 gA(4, 16, 8);   // (j-tile/64, i-tile/16, b)
  bepler_h_kernel<<<gA, dim3(256), 0, stream>>>(x, pl, (const uint4*)w1p, b1, hws);
  dim3 gB(8, 8, 8);    // (j-tile/32, i-tile/32, b)
  bepler_conv_kernel<<<gB, dim3(256), 0, stream>>>(hws, w2p, b2, pl, out);
}

// Round 6
// 143.087 us; speedup vs baseline: 1.0019x; 1.0019x over previous
//
#include <hip/hip_runtime.h>
#include <stdint.h>

#define LL 256
#define DD 256
#define CH 32

typedef __attribute__((ext_vector_type(2))) _Float16 f16x2;
typedef __attribute__((ext_vector_type(8))) _Float16 halfx8;
typedef __attribute__((ext_vector_type(4))) float f32x4;

static __device__ __forceinline__ uint32_t pk16(float a, float b) {
  f16x2 p; p.x = (_Float16)a; p.y = (_Float16)b;   // RTN casts
  return __builtin_bit_cast(uint32_t, p);
}
static __device__ __forceinline__ f16x2 bc2(uint32_t u) { return __builtin_bit_cast(f16x2, u); }
static __device__ __forceinline__ halfx8 bc8(uint4 u) { return __builtin_bit_cast(halfx8, u); }

// ---------------------------------------------------------------------------
// Kernel P: one-time packing.
//  blocks [0,256): x fp32 -> xf f16 (coalesced)
//  blocks [256,320): W1 -> w1p f16 in MFMA-A-frag layout (d-permutation):
//      d  = 32*(s>>1) + 8*g + 4*(s&1) + 2*((t>>2)&1) + (t&1),  g=(l>>4)
//      ko = (t&2) ? 256+d : d
//      flat[((s*2+hM)*64 + l)*8 + t] = W1[ko][16*hM + (l&15)]
//  block 320: W2 -> w2p packed f16 pairs [(di*4+q)*7+dj]*4 + t
// ---------------------------------------------------------------------------
__global__ void bepler_pack(const float* __restrict__ x, const float* __restrict__ W1,
                            const float* __restrict__ W2, _Float16* __restrict__ xf,
                            _Float16* __restrict__ w1p, uint32_t* __restrict__ w2p) {
  const int gid = blockIdx.x * 256 + threadIdx.x;
  if (blockIdx.x < 256) {
    const float4 f0 = ((const float4*)x)[gid * 2];
    const float4 f1 = ((const float4*)x)[gid * 2 + 1];
    uint4 v;
    v.x = pk16(f0.x, f0.y); v.y = pk16(f0.z, f0.w);
    v.z = pk16(f1.x, f1.y); v.w = pk16(f1.z, f1.w);
    ((uint4*)xf)[gid] = v;
  } else if (blockIdx.x < 320) {
    const int idx = gid - 65536;           // 0..16383
    const int t  = idx & 7;
    const int l  = (idx >> 3) & 63;
    const int hM = (idx >> 9) & 1;
    const int s  = idx >> 10;
    const int g  = (l >> 4) & 3;
    const int d  = 32 * (s >> 1) + 8 * g + 4 * (s & 1) + 2 * ((t >> 2) & 1) + (t & 1);
    const int ko = (t & 2) ? (DD + d) : d;
    w1p[idx] = (_Float16)W1[ko * CH + 16 * hM + (l & 15)];
  } else {
    for (int k = threadIdx.x; k < 784; k += 256) {
      const int t  = k & 3;
      const int dj = (k >> 2) % 7;
      const int qd = (k >> 2) / 7;         // di*4+q
      const int q  = qd & 3;
      const int di = qd >> 2;
      const int c  = q * 8 + 2 * t;
      w2p[k] = pk16(W2[(di * 7 + dj) * 32 + c], W2[(di * 7 + dj) * 32 + c + 1]);
    }
  }
}

// ---------------------------------------------------------------------------
// Kernel A: h[b,i,j,c] = mask * relu( z . W1[:,c] + b1[c] ), f16 out.
// Tile 16i x 64j (grid 512, 2 blocks/CU). Per m-step: 1 xi b128 broadcast +
// 4 xj b128 (<=2-way) feed 16 MFMA. afrags register-resident (128 VGPR).
// Epilogue: wave-private LDS transpose (row stride 38 f16 = 76 B) so global
// stores are dwordx4 with each wave-store covering 1 KB CONTIGUOUS -> full
// 64-B lines at HBM (no partial-line write amplification / write-allocate).
// ---------------------------------------------------------------------------
#define XPAD 280   // f16; 560 B/row = 35 granules -> <=2-way on b128 reads
#define TBS  (64 * 38)   // per-wave transpose buffer, f16 units (4864 B)
__global__ __launch_bounds__(256, 2) void bepler_h_kernel(
    const _Float16* __restrict__ xf, const int* __restrict__ plen,
    const uint4* __restrict__ w1p4, const float* __restrict__ b1,
    _Float16* __restrict__ hws)
{
  __shared__ _Float16 xi[16 * XPAD];   // 8.75 KB
  __shared__ _Float16 xj[64 * XPAD];   // 35 KB
  __shared__ _Float16 tb[4 * TBS];     // 19 KB transpose staging

  const int tid  = threadIdx.x;
  const int lane = tid & 63;
  const int wave = tid >> 6;
  const int b  = blockIdx.z;
  const int i0 = blockIdx.y * 16;
  const int j0 = blockIdx.x * 64;
  const int g   = lane >> 4;
  const int m16 = lane & 15;

  // Full W1 A-fragments from prepacked global (coalesced, L2-hot)
  uint4 af[16][2];
#pragma unroll
  for (int s = 0; s < 16; ++s) {
#pragma unroll
    for (int hM = 0; hM < 2; ++hM)
      af[s][hM] = w1p4[(s * 2 + hM) * 64 + lane];
  }

  // Stage x tiles: pure uint4 copies from pre-converted xf (L2-resident 1 MB)
  const _Float16* xfb = xf + (size_t)b * LL * DD;
  for (int idx = tid; idx < 80 * 32; idx += 256) {
    const int cg = idx & 31, row = idx >> 5;
    const int grow = (row < 16) ? (i0 + row) : (j0 + row - 16);
    const uint4 v = ((const uint4*)(xfb + grow * DD))[cg];
    _Float16* dst = (row < 16) ? (xi + row * XPAD) : (xj + (row - 16) * XPAD);
    ((uint4*)dst)[cg] = v;
  }

  const int len = plen[b];
  float b1v[2][4];
#pragma unroll
  for (int r = 0; r < 4; ++r) {
    b1v[0][r] = b1[g * 4 + r];        // c = (lane>>4)*4 + r        (hM=0)
    b1v[1][r] = b1[16 + g * 4 + r];   // c = 16 + (lane>>4)*4 + r   (hM=1)
  }
  __syncthreads();

  _Float16* tbw = tb + wave * TBS;

  for (int iu = 0; iu < 4; ++iu) {
    const int r = wave * 4 + iu;       // i-row in tile
    f32x4 acc[4][2];                   // [jg][hM]
#pragma unroll
    for (int jg = 0; jg < 4; ++jg)
#pragma unroll
      for (int hM = 0; hM < 2; ++hM)
        acc[jg][hM] = (f32x4){0.f, 0.f, 0.f, 0.f};

#pragma unroll
    for (int m = 0; m < 8; ++m) {
      const int doff = 32 * m + 8 * g;
      const uint4 ua = *(const uint4*)(xi + r * XPAD + doff);   // broadcast
      const f16x2 a0 = bc2(ua.x), a1 = bc2(ua.y), a2 = bc2(ua.z), a3 = bc2(ua.w);
#pragma unroll
      for (int jg = 0; jg < 4; ++jg) {
        const uint4 uc = *(const uint4*)(xj + (jg * 16 + m16) * XPAD + doff);
        const f16x2 c0 = bc2(uc.x), c1 = bc2(uc.y), c2 = bc2(uc.z), c3 = bc2(uc.w);
        const f16x2 p0 = a0 * c0, p1 = a1 * c1, p2 = a2 * c2, p3 = a3 * c3;
        const uint32_t s0 = __builtin_bit_cast(uint32_t, a0 - c0) & 0x7FFF7FFFu;
        const uint32_t s1 = __builtin_bit_cast(uint32_t, a1 - c1) & 0x7FFF7FFFu;
        const uint32_t s2 = __builtin_bit_cast(uint32_t, a2 - c2) & 0x7FFF7FFFu;
        const uint32_t s3 = __builtin_bit_cast(uint32_t, a3 - c3) & 0x7FFF7FFFu;
        uint4 be, bo;
        be.x = __builtin_bit_cast(uint32_t, p0); be.y = s0;
        be.z = __builtin_bit_cast(uint32_t, p1); be.w = s1;
        bo.x = __builtin_bit_cast(uint32_t, p2); bo.y = s2;
        bo.z = __builtin_bit_cast(uint32_t, p3); bo.w = s3;
        const halfx8 bE = bc8(be), bO = bc8(bo);
        acc[jg][0] = __builtin_amdgcn_mfma_f32_16x16x32_f16(bc8(af[2 * m][0]),     bE, acc[jg][0], 0, 0, 0);
        acc[jg][1] = __builtin_amdgcn_mfma_f32_16x16x32_f16(bc8(af[2 * m][1]),     bE, acc[jg][1], 0, 0, 0);
        acc[jg][0] = __builtin_amdgcn_mfma_f32_16x16x32_f16(bc8(af[2 * m + 1][0]), bO, acc[jg][0], 0, 0, 0);
        acc[jg][1] = __builtin_amdgcn_mfma_f32_16x16x32_f16(bc8(af[2 * m + 1][1]), bO, acc[jg][1], 0, 0, 0);
      }
    }

    const int i = i0 + r;
    // Phase 1: scatter into wave-private LDS transpose buffer.
    // D layout: c = 16*hM + g*4 + reg ; j = jg*16 + m16 (local).
#pragma unroll
    for (int jg = 0; jg < 4; ++jg) {
      const int jl = jg * 16 + m16;
      const float msk = (i < len && (j0 + jl) < len) ? 1.f : 0.f;
#pragma unroll
      for (int hM = 0; hM < 2; ++hM) {
        const f32x4 a = acc[jg][hM];
        uint2 st;
        st.x = pk16(fmaxf(a[0] + b1v[hM][0], 0.f) * msk,
                    fmaxf(a[1] + b1v[hM][1], 0.f) * msk);
        st.y = pk16(fmaxf(a[2] + b1v[hM][2], 0.f) * msk,
                    fmaxf(a[3] + b1v[hM][3], 0.f) * msk);
        *(uint2*)(tbw + jl * 38 + hM * 16 + g * 4) = st;
      }
    }
    // Phase 2: gather rows, store contiguous 1 KB per wave-store.
    // (wave-private buffer; DS pipe is in-order per wave -> no barrier)
#pragma unroll
    for (int s = 0; s < 4; ++s) {
      const int jl = s * 16 + (lane >> 2);   // 0..63
      const int ch = lane & 3;               // 16-B chunk within 64-B channel vec
      const uint4 v = *(const uint4*)(tbw + jl * 38 + ch * 8);
      *(uint4*)(hws + ((size_t)(b * LL + i) * LL + (j0 + jl)) * CH + ch * 8) = v;
    }
  }
}

// ---------------------------------------------------------------------------
// Kernel B: out[b,i,j] = mask * ( sum_{di,dj,c} h[..]*W2[di,dj,c] + b2 )
// 32x32 tile (grid 512, 2 blocks/CU), halo 38x38, 2 ch-phases (16ch each).
// Thread = 1i x 4j outputs. Weights wave-uniform -> s_load; pk_fma f16 acc.
// ---------------------------------------------------------------------------
__global__ __launch_bounds__(256, 2) void bepler_conv_kernel(
    const _Float16* __restrict__ hws, const uint32_t* __restrict__ w2p,
    const float* __restrict__ b2, const int* __restrict__ plen,
    float* __restrict__ out)
{
  __shared__ _Float16 htile[2 * 38 * 39 * 8];   // 47,424 B

  const int tid = threadIdx.x;
  const int b   = blockIdx.z;
  const int i0  = blockIdx.y * 32;
  const int j0  = blockIdx.x * 32;
  const int ti  = tid & 31;        // output row in tile
  const int tj  = tid >> 5;        // output cols 4*tj .. 4*tj+3

  f16x2 acc[4][4];                 // [jj][ch-pair]
#pragma unroll
  for (int jj = 0; jj < 4; ++jj)
#pragma unroll
    for (int t = 0; t < 4; ++t) acc[jj][t] = (f16x2){(_Float16)0, (_Float16)0};

  for (int ph = 0; ph < 2; ++ph) {         // channel phases (16 ch each)
    if (ph) __syncthreads();               // drain phase-0 reads
    for (int idx = tid; idx < 2 * 38 * 38; idx += 256) {
      const int qq  = idx & 1;
      const int pos = idx >> 1;
      const int row = pos / 38, col = pos - row * 38;
      const int gi = i0 - 3 + row, gj = j0 - 3 + col;
      uint4 v = make_uint4(0u, 0u, 0u, 0u);
      if (gi >= 0 && gi < LL && gj >= 0 && gj < LL)
        v = *(const uint4*)(hws + (((size_t)(b * LL + gi) * LL + gj) * CH + ph * 16 + qq * 8));
      *(uint4*)(htile + ((qq * 38 + row) * 39 + col) * 8) = v;
    }
    __syncthreads();

    for (int r = 0; r < 7; ++r) {          // di = r (wave-uniform)
#pragma unroll
      for (int qq = 0; qq < 2; ++qq) {
        const _Float16* hrow = htile + ((qq * 38 + ti + r) * 39 + 4 * tj) * 8;
        const uint32_t* wr = w2p + ((r * 4 + ph * 2 + qq) * 7) * 4;  // uniform
#pragma unroll
        for (int c = 0; c < 10; ++c) {
          const uint4 u = *(const uint4*)(hrow + c * 8);
          const f16x2 h0 = bc2(u.x), h1 = bc2(u.y), h2 = bc2(u.z), h3 = bc2(u.w);
#pragma unroll
          for (int jj = 0; jj < 4; ++jj) {
            const int dj = c - jj;                   // compile-time
            if (dj >= 0 && dj < 7) {
              const uint32_t* w = wr + dj * 4;
              acc[jj][0] = __builtin_elementwise_fma(h0, bc2(w[0]), acc[jj][0]);
              acc[jj][1] = __builtin_elementwise_fma(h1, bc2(w[1]), acc[jj][1]);
              acc[jj][2] = __builtin_elementwise_fma(h2, bc2(w[2]), acc[jj][2]);
              acc[jj][3] = __builtin_elementwise_fma(h3, bc2(w[3]), acc[jj][3]);
            }
          }
        }
      }
    }
  }

  const int i = i0 + ti;
  const int jb = j0 + 4 * tj;
  const int len = plen[b];
  const float bias = b2[0];
  float4 o;
  float s[4];
#pragma unroll
  for (int jj = 0; jj < 4; ++jj) {
    float v = 0.f;
#pragma unroll
    for (int t = 0; t < 4; ++t) v += (float)acc[jj][t].x + (float)acc[jj][t].y;
    s[jj] = v;
  }
  o.x = (i < len && (jb + 0) < len) ? s[0] + bias : 0.f;
  o.y = (i < len && (jb + 1) < len) ? s[1] + bias : 0.f;
  o.z = (i < len && (jb + 2) < len) ? s[2] + bias : 0.f;
  o.w = (i < len && (jb + 3) < len) ? s[3] + bias : 0.f;
  *(float4*)(out + (size_t)(b * LL + i) * LL + jb) = o;
}

extern "C" void kernel_launch(void* const* d_in, const int* in_sizes, int n_in,
                              void* d_out, int out_size, void* d_ws, size_t ws_size,
                              hipStream_t stream) {
  const float* x   = (const float*)d_in[0];
  const int*   pl  = (const int*)d_in[1];
  const float* W1  = (const float*)d_in[2];
  const float* b1  = (const float*)d_in[3];
  const float* W2  = (const float*)d_in[4];
  const float* b2  = (const float*)d_in[5];
  float* out = (float*)d_out;

  _Float16* hws = (_Float16*)d_ws;                      // 33,554,432 B
  _Float16* w1p = (_Float16*)((char*)d_ws + 33554432);  // 32,768 B
  uint32_t* w2p = (uint32_t*)((char*)d_ws + 33587200);  // 3,136 B
  _Float16* xf  = (_Float16*)((char*)d_ws + 33591296);  // 1,048,576 B

  bepler_pack<<<dim3(321), dim3(256), 0, stream>>>(x, W1, W2, xf, w1p, w2p);
  dim3 gA(4, 16, 8);   // (j-tile/64, i-tile/16, b)
  bepler_h_kernel<<<gA, dim3(256), 0, stream>>>(xf, pl, (const uint4*)w1p, b1, hws);
  dim3 gB(8, 8, 8);    // (j-tile/32, i-tile/32, b)
  bepler_conv_kernel<<<gB, dim3(256), 0, stream>>>(hws, w2p, b2, pl, out);
}